// Round 11
// baseline (6205.669 us; speedup 1.0000x reference)
//
#include <hip/hip_runtime.h>

#define B_   64
#define C_   256
#define D_   128
#define HW_  1024
#define K_   1024
#define N_   65536
#define MARGIN_PREF 1.2e-3f

typedef __attribute__((ext_vector_type(8))) short short8;
typedef __attribute__((ext_vector_type(4))) float f32x4;

__device__ __forceinline__ unsigned short f2bf(float f) {   // RNE f32->bf16
    unsigned u = __float_as_uint(f);
    return (unsigned short)((u + 0x7FFFu + ((u >> 16) & 1u)) >> 16);
}
__device__ __forceinline__ unsigned long long packdk(float d, int k) {  // order-preserving
    unsigned u = __float_as_uint(d);
    u = (u & 0x80000000u) ? ~u : (u | 0x80000000u);
    return ((unsigned long long)u << 10) | (unsigned)k;
}
__device__ __forceinline__ unsigned long long min64(unsigned long long a, unsigned long long b) {
    return a < b ? a : b;
}

// numpy pairwise-sum emulation, n=128 — scalar 8-accumulator tree (verified R4-R10)
template <typename F>
__device__ __forceinline__ float np_sum128(F ld) {
#pragma clang fp contract(off)
    float r0 = ld(0), r1 = ld(1), r2 = ld(2), r3 = ld(3);
    float r4 = ld(4), r5 = ld(5), r6 = ld(6), r7 = ld(7);
#pragma unroll
    for (int i = 8; i < 128; i += 8) {
        r0 = r0 + ld(i + 0); r1 = r1 + ld(i + 1);
        r2 = r2 + ld(i + 2); r3 = r3 + ld(i + 3);
        r4 = r4 + ld(i + 4); r5 = r5 + ld(i + 5);
        r6 = r6 + ld(i + 6); r7 = r7 + ld(i + 7);
    }
    return ((r0 + r1) + (r2 + r3)) + ((r4 + r5) + (r6 + r7));
}

// ---------------- K0: enorm (np bins) + embed -> bf16 ----------------
__global__ __launch_bounds__(256) void k0_norms(const float* __restrict__ embed,
                                                float* __restrict__ enorm,
                                                unsigned short* __restrict__ ebf) {
#pragma clang fp contract(off)
    int k = blockIdx.x * 256 + threadIdx.x;
    if (k >= K_) return;
    const float* e = embed + (size_t)k * D_;
    enorm[k] = np_sum128([&](int i) { float v = e[i]; return v * v; });
#pragma unroll 8
    for (int i = 0; i < 128; ++i) ebf[(size_t)k * 128 + i] = f2bf(e[i]);
}

// ---------------- K1: einsum-f32 emulation (sequential c, mul+add, no FMA) + bf16 copy ----------------
__global__ __launch_bounds__(256) void k1_proj(const float* __restrict__ z,
                                               const float* __restrict__ w,
                                               const float* __restrict__ bias,
                                               float* __restrict__ zp,
                                               unsigned short* __restrict__ zbf) {
#pragma clang fp contract(off)
    __shared__ float zs[64][64];
    __shared__ float wsh[64][128];
    const int b   = blockIdx.x >> 4;
    const int hw0 = (blockIdx.x & 15) << 6;
    const int t   = threadIdx.x;
    const int hwg = (t & 7) * 8;
    const int dg  = (t >> 3) * 4;

    float acc[8][4];
#pragma unroll
    for (int i = 0; i < 8; ++i)
#pragma unroll
        for (int j = 0; j < 4; ++j) acc[i][j] = 0.f;

    for (int ct = 0; ct < C_; ct += 64) {
        __syncthreads();
#pragma unroll
        for (int i = 0; i < 16; ++i) {
            int idx = i * 256 + t;
            int cc = idx >> 6, hwl = idx & 63;
            zs[cc][hwl] = z[(((size_t)b * C_ + ct + cc) << 10) + hw0 + hwl];
        }
#pragma unroll
        for (int i = 0; i < 32; ++i) {
            int idx = i * 256 + t;
            int cc = idx >> 7, d = idx & 127;
            wsh[cc][d] = w[(size_t)d * C_ + ct + cc];
        }
        __syncthreads();
#pragma unroll 2
        for (int cc = 0; cc < 64; ++cc) {
            float4 za = *(const float4*)&zs[cc][hwg];
            float4 zb = *(const float4*)&zs[cc][hwg + 4];
            float4 wv = *(const float4*)&wsh[cc][dg];
            float zv[8]  = {za.x, za.y, za.z, za.w, zb.x, zb.y, zb.z, zb.w};
            float wva[4] = {wv.x, wv.y, wv.z, wv.w};
#pragma unroll
            for (int i = 0; i < 8; ++i)
#pragma unroll
                for (int j = 0; j < 4; ++j) {
                    float p = zv[i] * wva[j];
                    acc[i][j] = acc[i][j] + p;
                }
        }
    }
#pragma unroll
    for (int i = 0; i < 8; ++i)
#pragma unroll
        for (int j = 0; j < 4; ++j) {
            float v = acc[i][j] + bias[dg + j];
            size_t off = (((size_t)b * HW_ + hw0 + hwg + i) << 7) + dg + j;
            zp[off]  = v;
            zbf[off] = f2bf(v);
        }
}

// ---------------- K0z: znorm[n] = np.sum(zf*zf) per row (np bins) ----------------
__global__ __launch_bounds__(256) void k0z_znorm(const float* __restrict__ zp,
                                                 float* __restrict__ znorm) {
#pragma clang fp contract(off)
    __shared__ float zl[64][129];          // +1 pad: conflict-free column reads
    const int t = threadIdx.x, n0 = blockIdx.x * 64;
#pragma unroll
    for (int i = 0; i < 32; ++i) {
        int idx = i * 256 + t;
        zl[idx >> 7][idx & 127] = zp[(size_t)n0 * 128 + idx];
    }
    __syncthreads();
    if (t < 64)
        znorm[n0 + t] = np_sum128([&](int i) { float v = zl[t][i]; return v * v; });
}

// ---------------- K2: single-pass MFMA prefilter + exact np-bin rescue ----------------
// R9 structure (proven: LDS-staged e-tile shared by 4 waves, zfrag in regs),
// minus its overheads: ONE pass (running-min candidate window, proven R10) and
// double-buffered staging with 1 barrier/kt (issue-early / ds_write-late).
__global__ __launch_bounds__(256) void k2_argmin(const unsigned short* __restrict__ zbf,
                                                 const unsigned short* __restrict__ ebf,
                                                 const float* __restrict__ zp,
                                                 const float* __restrict__ embed,
                                                 const float* __restrict__ enorm,
                                                 const float* __restrict__ znorm,
                                                 int* __restrict__ bestk_ws,
                                                 float* __restrict__ out_idx) {
    __shared__ unsigned char etile[2][16 * 272];
    const int t   = threadIdx.x;
    const int l   = t & 63;
    const int wid = t >> 6;
    const int r0  = blockIdx.x * 128 + wid * 32;   // wave's 32 rows (2 row-tiles)
    const int lr  = l & 15;
    const int lh  = l >> 4;

    // z fragments (B operand): 2 row-tiles x 4 d-tiles (verified mapping, R9/R10)
    short8 zfrag[2][4];
#pragma unroll
    for (int rt = 0; rt < 2; ++rt)
#pragma unroll
        for (int dt = 0; dt < 4; ++dt)
            zfrag[rt][dt] = *(const short8*)(zbf + (((size_t)(r0 + rt * 16 + lr)) << 7) + dt * 32 + lh * 8);

    // staging geometry: 256 threads x 16B = one 16x128 bf16 tile
    const int srow = t >> 4, scol = t & 15;
    const size_t gsrc = ((size_t)srow << 7) + scol * 8;     // element offset in tile
    const int    sdst = srow * 272 + scol * 16;             // byte offset in buffer

    // prologue: stage kt=0 into buf0
    {
        short8 s0 = *(const short8*)(ebf + gsrc);
        *(short8*)(etile[0] + sdst) = s0;
    }

    float bmin0 = 1e30f, bmin1 = 1e30f;
    unsigned long long ca0 = 0, cb0 = 0, ca1 = 0, cb1 = 0;  // 12 slots per row-tile
    int cnt0 = 0, cnt1 = 0;

#pragma unroll 1
    for (int kt = 0; kt < 64; ++kt) {
        __syncthreads();                                    // buf[kt&1] ready
        short8 nxt;
        if (kt < 63)                                        // issue next-tile load early
            nxt = *(const short8*)(ebf + (((size_t)(kt + 1) * 16) << 7) + gsrc);

        const unsigned char* buf = etile[kt & 1];
        short8 af[4];
#pragma unroll
        for (int dt = 0; dt < 4; ++dt)
            af[dt] = *(const short8*)(buf + lr * 272 + dt * 64 + lh * 16);
        f32x4 en4 = *(const f32x4*)(enorm + kt * 16 + lh * 4);

        f32x4 acc0 = {0.f, 0.f, 0.f, 0.f};
        f32x4 acc1 = {0.f, 0.f, 0.f, 0.f};
#pragma unroll
        for (int dt = 0; dt < 4; ++dt)
            acc0 = __builtin_amdgcn_mfma_f32_16x16x32_bf16(af[dt], zfrag[0][dt], acc0, 0, 0, 0);
#pragma unroll
        for (int dt = 0; dt < 4; ++dt)
            acc1 = __builtin_amdgcn_mfma_f32_16x16x32_bf16(af[dt], zfrag[1][dt], acc1, 0, 0, 0);

#pragma unroll
        for (int reg = 0; reg < 4; ++reg) {
            int kk = kt * 16 + lh * 4 + reg;
            float d0 = fmaf(-2.f, acc0[reg], en4[reg]);
            if (d0 < bmin0 + MARGIN_PREF) {                 // running-min window (superset)
                if (cnt0 < 6)       ca0 |= (unsigned long long)kk << (10 * cnt0);
                else if (cnt0 < 12) cb0 |= (unsigned long long)kk << (10 * (cnt0 - 6));
                ++cnt0;
                bmin0 = fminf(bmin0, d0);
            }
            float d1 = fmaf(-2.f, acc1[reg], en4[reg]);
            if (d1 < bmin1 + MARGIN_PREF) {
                if (cnt1 < 6)       ca1 |= (unsigned long long)kk << (10 * cnt1);
                else if (cnt1 < 12) cb1 |= (unsigned long long)kk << (10 * (cnt1 - 6));
                ++cnt1;
                bmin1 = fminf(bmin1, d1);
            }
        }

        if (kt < 63)                                        // write-late into other buffer
            *(short8*)(etile[(kt + 1) & 1] + sdst) = nxt;
    }

    // ---- exact np-bin refine of candidates (R4-verified chain) ----
    unsigned long long fin[2];
#pragma unroll
    for (int rt = 0; rt < 2; ++rt) {
        const int myrow = r0 + rt * 16 + lr;
        const float* zrow = zp + ((size_t)myrow << 7);
        const float  zn   = znorm[myrow];
        unsigned long long best = ~0ull;
        unsigned long long ca = rt == 0 ? ca0 : ca1, cb = rt == 0 ? cb0 : cb1;
        int cnt = rt == 0 ? cnt0 : cnt1;

        auto refine = [&](int kk) {
#pragma clang fp contract(off)
            const float* e = embed + ((size_t)kk << 7);
            float s = 0.f;
#pragma unroll 1
            for (int d = 0; d < 128; ++d) s = fmaf(zrow[d], e[d], s);
            float T  = 2.0f * s;
            float A  = zn - T;                  // bin-maker 1 (mag ~13)
            float Bv = A + enorm[kk];           // bin-maker 2
            best = min64(best, packdk(Bv, kk)); // lex (bin, k) = np first-occurrence
        };

        if (cnt <= 12) {
#pragma unroll
            for (int i = 0; i < 6; ++i)
                if (i < cnt) refine((int)((ca >> (10 * i)) & 1023ull));
#pragma unroll
            for (int i = 6; i < 12; ++i)
                if (i < cnt) refine((int)((cb >> (10 * (i - 6))) & 1023ull));
        } else {                                // overflow fallback: lane's whole 256-k subset
#pragma unroll 1
            for (int kt = 0; kt < 64; ++kt)
#pragma unroll
                for (int reg = 0; reg < 4; ++reg) refine(kt * 16 + lh * 4 + reg);
        }
        unsigned long long o;
        o = __shfl_xor(best, 16, 64); best = min64(best, o);
        o = __shfl_xor(best, 32, 64); best = min64(best, o);
        fin[rt] = best;
    }

    if (l < 16) {
#pragma unroll
        for (int rt = 0; rt < 2; ++rt) {
            int row = r0 + rt * 16 + l;
            int kk  = (int)(fin[rt] & 1023ull);
            bestk_ws[row] = kk;
            out_idx[row]  = (float)kk;
        }
    }
}

// ---------------- K3: gather + NCHW transpose ----------------
__global__ __launch_bounds__(256) void k3_gather(const float* __restrict__ embed,
                                                 const int* __restrict__ bestk,
                                                 float* __restrict__ out0) {
    __shared__ float tile[64][129];
    const int b   = blockIdx.x >> 4;
    const int hw0 = (blockIdx.x & 15) << 6;
    const int t   = threadIdx.x;
    const int n0  = b * HW_ + hw0;
#pragma unroll
    for (int i = 0; i < 32; ++i) {
        int idx = i * 256 + t;
        int hwl = idx >> 7, d = idx & 127;
        int k = bestk[n0 + hwl];
        tile[hwl][d] = embed[(size_t)k * 128 + d];
    }
    __syncthreads();
#pragma unroll
    for (int i = 0; i < 32; ++i) {
        int idx = i * 256 + t;
        int d = idx >> 6, hwl = idx & 63;
        out0[(((size_t)b * D_ + d) << 10) + hw0 + hwl] = tile[hwl][d];
    }
}

extern "C" void kernel_launch(void* const* d_in, const int* in_sizes, int n_in,
                              void* d_out, int out_size, void* d_ws, size_t ws_size,
                              hipStream_t stream) {
    const float* z     = (const float*)d_in[0];
    const float* pw    = (const float*)d_in[1];
    const float* pb    = (const float*)d_in[2];
    const float* embed = (const float*)d_in[3];

    float* out0 = (float*)d_out;
    float* out1 = (float*)d_out + (size_t)B_ * D_ * HW_;

    char* ws = (char*)d_ws;
    float*          zp    = (float*)ws;                                   // 32 MB
    unsigned short* zbf   = (unsigned short*)(ws + (32u << 20));          // 16 MB
    unsigned short* ebf   = (unsigned short*)(ws + (48u << 20));          // 256 KB
    float*          enorm = (float*)(ws + (48u << 20) + (256u << 10));    // 4 KB
    float*          znorm = (float*)(ws + (49u << 20));                   // 256 KB
    int*            bestk = (int*)  (ws + (50u << 20));                   // 256 KB

    hipLaunchKernelGGL(k0_norms,  dim3(4),    dim3(256), 0, stream, embed, enorm, ebf);
    hipLaunchKernelGGL(k1_proj,   dim3(1024), dim3(256), 0, stream, z, pw, pb, zp, zbf);
    hipLaunchKernelGGL(k0z_znorm, dim3(1024), dim3(256), 0, stream, zp, znorm);
    hipLaunchKernelGGL(k2_argmin, dim3(512),  dim3(256), 0, stream,
                       zbf, ebf, zp, embed, enorm, znorm, bestk, out1);
    hipLaunchKernelGGL(k3_gather, dim3(1024), dim3(256), 0, stream, embed, bestk, out0);
}

// Round 12
// 390.338 us; speedup vs baseline: 15.8982x; 15.8982x over previous
//
#include <hip/hip_runtime.h>

#define B_   64
#define C_   256
#define D_   128
#define HW_  1024
#define K_   1024
#define N_   65536
#define MARGIN_PREF 1.2e-3f

typedef __attribute__((ext_vector_type(8))) short short8;
typedef __attribute__((ext_vector_type(4))) float f32x4;

__device__ __forceinline__ unsigned short f2bf(float f) {   // RNE f32->bf16
    unsigned u = __float_as_uint(f);
    return (unsigned short)((u + 0x7FFFu + ((u >> 16) & 1u)) >> 16);
}
__device__ __forceinline__ unsigned long long packdk(float d, int k) {  // order-preserving
    unsigned u = __float_as_uint(d);
    u = (u & 0x80000000u) ? ~u : (u | 0x80000000u);
    return ((unsigned long long)u << 10) | (unsigned)k;
}
__device__ __forceinline__ float unpackd(unsigned long long key) {
    unsigned u = (unsigned)(key >> 10);
    u = (u & 0x80000000u) ? (u ^ 0x80000000u) : ~u;
    return __uint_as_float(u);
}
__device__ __forceinline__ unsigned long long min64(unsigned long long a, unsigned long long b) {
    return a < b ? a : b;
}

// numpy pairwise-sum emulation, n=128 — scalar 8-accumulator tree (verified R4-R11)
template <typename F>
__device__ __forceinline__ float np_sum128(F ld) {
#pragma clang fp contract(off)
    float r0 = ld(0), r1 = ld(1), r2 = ld(2), r3 = ld(3);
    float r4 = ld(4), r5 = ld(5), r6 = ld(6), r7 = ld(7);
#pragma unroll
    for (int i = 8; i < 128; i += 8) {
        r0 = r0 + ld(i + 0); r1 = r1 + ld(i + 1);
        r2 = r2 + ld(i + 2); r3 = r3 + ld(i + 3);
        r4 = r4 + ld(i + 4); r5 = r5 + ld(i + 5);
        r6 = r6 + ld(i + 6); r7 = r7 + ld(i + 7);
    }
    return ((r0 + r1) + (r2 + r3)) + ((r4 + r5) + (r6 + r7));
}

// ---------------- K0: enorm (np bins) + embed -> bf16 ----------------
__global__ __launch_bounds__(256) void k0_norms(const float* __restrict__ embed,
                                                float* __restrict__ enorm,
                                                unsigned short* __restrict__ ebf) {
#pragma clang fp contract(off)
    int k = blockIdx.x * 256 + threadIdx.x;
    if (k >= K_) return;
    const float* e = embed + (size_t)k * D_;
    enorm[k] = np_sum128([&](int i) { float v = e[i]; return v * v; });
#pragma unroll 8
    for (int i = 0; i < 128; ++i) ebf[(size_t)k * 128 + i] = f2bf(e[i]);
}

// ---------------- K1: einsum-f32 emulation (sequential c, mul+add, no FMA) + bf16 copy ----------------
__global__ __launch_bounds__(256) void k1_proj(const float* __restrict__ z,
                                               const float* __restrict__ w,
                                               const float* __restrict__ bias,
                                               float* __restrict__ zp,
                                               unsigned short* __restrict__ zbf) {
#pragma clang fp contract(off)
    __shared__ float zs[64][64];
    __shared__ float wsh[64][128];
    const int b   = blockIdx.x >> 4;
    const int hw0 = (blockIdx.x & 15) << 6;
    const int t   = threadIdx.x;
    const int hwg = (t & 7) * 8;
    const int dg  = (t >> 3) * 4;

    float acc[8][4];
#pragma unroll
    for (int i = 0; i < 8; ++i)
#pragma unroll
        for (int j = 0; j < 4; ++j) acc[i][j] = 0.f;

    for (int ct = 0; ct < C_; ct += 64) {
        __syncthreads();
#pragma unroll
        for (int i = 0; i < 16; ++i) {
            int idx = i * 256 + t;
            int cc = idx >> 6, hwl = idx & 63;
            zs[cc][hwl] = z[(((size_t)b * C_ + ct + cc) << 10) + hw0 + hwl];
        }
#pragma unroll
        for (int i = 0; i < 32; ++i) {
            int idx = i * 256 + t;
            int cc = idx >> 7, d = idx & 127;
            wsh[cc][d] = w[(size_t)d * C_ + ct + cc];
        }
        __syncthreads();
#pragma unroll 2
        for (int cc = 0; cc < 64; ++cc) {
            float4 za = *(const float4*)&zs[cc][hwg];
            float4 zb = *(const float4*)&zs[cc][hwg + 4];
            float4 wv = *(const float4*)&wsh[cc][dg];
            float zv[8]  = {za.x, za.y, za.z, za.w, zb.x, zb.y, zb.z, zb.w};
            float wva[4] = {wv.x, wv.y, wv.z, wv.w};
#pragma unroll
            for (int i = 0; i < 8; ++i)
#pragma unroll
                for (int j = 0; j < 4; ++j) {
                    float p = zv[i] * wva[j];
                    acc[i][j] = acc[i][j] + p;
                }
        }
    }
#pragma unroll
    for (int i = 0; i < 8; ++i)
#pragma unroll
        for (int j = 0; j < 4; ++j) {
            float v = acc[i][j] + bias[dg + j];
            size_t off = (((size_t)b * HW_ + hw0 + hwg + i) << 7) + dg + j;
            zp[off]  = v;
            zbf[off] = f2bf(v);
        }
}

// ---------------- K0z: znorm[n] = np.sum(zf*zf) per row (np bins) ----------------
__global__ __launch_bounds__(256) void k0z_znorm(const float* __restrict__ zp,
                                                 float* __restrict__ znorm) {
#pragma clang fp contract(off)
    __shared__ float zl[64][129];          // +1 pad: conflict-free column reads
    const int t = threadIdx.x, n0 = blockIdx.x * 64;
#pragma unroll
    for (int i = 0; i < 32; ++i) {
        int idx = i * 256 + t;
        zl[idx >> 7][idx & 127] = zp[(size_t)n0 * 128 + idx];
    }
    __syncthreads();
    if (t < 64)
        znorm[n0 + t] = np_sum128([&](int i) { float v = zl[t][i]; return v * v; });
}

// ---------------- K2: R9 structure, tuned ----------------
// Two passes (A: min-only, branch-free; B: recompute + collect) — the only
// regalloc-stable shape (R9 proved; R10/R11 one-pass variants collapsed).
// Tuning vs R9: 1024 blocks (16 rows/wave, 1 row-tile -> less state, 2x blocks/CU)
// and 32-k supertiles (half the barriers).
__global__ __launch_bounds__(256) void k2_argmin(const unsigned short* __restrict__ zbf,
                                                 const unsigned short* __restrict__ ebf,
                                                 const float* __restrict__ zp,
                                                 const float* __restrict__ embed,
                                                 const float* __restrict__ enorm,
                                                 const float* __restrict__ znorm,
                                                 int* __restrict__ bestk_ws,
                                                 float* __restrict__ out_idx) {
    __shared__ unsigned char etile[32 * 272];      // 32 k x 128 d bf16, 272B rows
    const int t   = threadIdx.x;
    const int l   = t & 63;
    const int wid = t >> 6;
    const int r0  = (blockIdx.x * 4 + wid) * 16;   // wave's 16 rows
    const int lr  = l & 15;
    const int lh  = l >> 4;

    // z fragments (B operand): 4 d-tiles (mapping verified R9-R11)
    short8 zfrag[4];
#pragma unroll
    for (int dt = 0; dt < 4; ++dt)
        zfrag[dt] = *(const short8*)(zbf + (((size_t)(r0 + lr)) << 7) + dt * 32 + lh * 8);

    const int srow = t >> 4, scol = t & 15;        // staging: 2 rows x 16B per thread

    // ---- Pass A: running min of packed (dist,k) — branch-free ----
    unsigned long long bk = ~0ull;
#pragma unroll 1
    for (int st = 0; st < 32; ++st) {
        __syncthreads();
#pragma unroll
        for (int i = 0; i < 2; ++i) {
            int row = i * 16 + srow;
            *(short8*)(etile + row * 272 + scol * 16) =
                *(const short8*)(ebf + (((size_t)(st * 32 + row)) << 7) + scol * 8);
        }
        __syncthreads();
#pragma unroll
        for (int ks = 0; ks < 2; ++ks) {
            short8 af[4];
#pragma unroll
            for (int dt = 0; dt < 4; ++dt)
                af[dt] = *(const short8*)(etile + (ks * 16 + lr) * 272 + dt * 64 + lh * 16);
            f32x4 en4 = *(const f32x4*)(enorm + st * 32 + ks * 16 + lh * 4);
            f32x4 acc = {0.f, 0.f, 0.f, 0.f};
#pragma unroll
            for (int dt = 0; dt < 4; ++dt)
                acc = __builtin_amdgcn_mfma_f32_16x16x32_bf16(af[dt], zfrag[dt], acc, 0, 0, 0);
#pragma unroll
            for (int reg = 0; reg < 4; ++reg) {
                float dist = fmaf(-2.f, acc[reg], en4[reg]);
                bk = min64(bk, packdk(dist, st * 32 + ks * 16 + lh * 4 + reg));
            }
        }
    }
    {   // row-min across lanes {lr, lr+16, lr+32, lr+48}
        unsigned long long o;
        o = __shfl_xor(bk, 16, 64); bk = min64(bk, o);
        o = __shfl_xor(bk, 32, 64); bk = min64(bk, o);
    }
    const float thr = unpackd(bk) + MARGIN_PREF;

    // ---- Pass B: bitwise-identical recompute, collect candidates ----
    unsigned long long ca = 0, cb = 0;             // 12 x 10-bit candidate slots
    int cnt = 0;
#pragma unroll 1
    for (int st = 0; st < 32; ++st) {
        __syncthreads();
#pragma unroll
        for (int i = 0; i < 2; ++i) {
            int row = i * 16 + srow;
            *(short8*)(etile + row * 272 + scol * 16) =
                *(const short8*)(ebf + (((size_t)(st * 32 + row)) << 7) + scol * 8);
        }
        __syncthreads();
#pragma unroll
        for (int ks = 0; ks < 2; ++ks) {
            short8 af[4];
#pragma unroll
            for (int dt = 0; dt < 4; ++dt)
                af[dt] = *(const short8*)(etile + (ks * 16 + lr) * 272 + dt * 64 + lh * 16);
            f32x4 en4 = *(const f32x4*)(enorm + st * 32 + ks * 16 + lh * 4);
            f32x4 acc = {0.f, 0.f, 0.f, 0.f};
#pragma unroll
            for (int dt = 0; dt < 4; ++dt)
                acc = __builtin_amdgcn_mfma_f32_16x16x32_bf16(af[dt], zfrag[dt], acc, 0, 0, 0);
#pragma unroll
            for (int reg = 0; reg < 4; ++reg) {
                float dist = fmaf(-2.f, acc[reg], en4[reg]);
                if (dist < thr) {
                    int kk = st * 32 + ks * 16 + lh * 4 + reg;
                    if (cnt < 6)       ca |= (unsigned long long)kk << (10 * cnt);
                    else if (cnt < 12) cb |= (unsigned long long)kk << (10 * (cnt - 6));
                    ++cnt;
                }
            }
        }
    }

    // ---- Phase C: exact np-bin refine of candidates (R4-verified chain) ----
    const int myrow = r0 + lr;
    const float* zrow = zp + ((size_t)myrow << 7);
    const float  zn   = znorm[myrow];
    unsigned long long best = ~0ull;

    auto refine = [&](int kk) {
#pragma clang fp contract(off)
        const float* e = embed + ((size_t)kk << 7);
        float s = 0.f;
#pragma unroll 1
        for (int d = 0; d < 128; ++d) s = fmaf(zrow[d], e[d], s);
        float T  = 2.0f * s;
        float A  = zn - T;                  // bin-maker 1 (mag ~13)
        float Bv = A + enorm[kk];           // bin-maker 2
        best = min64(best, packdk(Bv, kk)); // lex (bin, k) = np first-occurrence
    };

    if (cnt <= 12) {
#pragma unroll
        for (int i = 0; i < 6; ++i)
            if (i < cnt) refine((int)((ca >> (10 * i)) & 1023ull));
#pragma unroll
        for (int i = 6; i < 12; ++i)
            if (i < cnt) refine((int)((cb >> (10 * (i - 6))) & 1023ull));
    } else {                                // overflow fallback: lane's whole 256-k subset
#pragma unroll 1
        for (int kt = 0; kt < 64; ++kt)
#pragma unroll
            for (int reg = 0; reg < 4; ++reg) refine(kt * 16 + lh * 4 + reg);
    }
    {
        unsigned long long o;
        o = __shfl_xor(best, 16, 64); best = min64(best, o);
        o = __shfl_xor(best, 32, 64); best = min64(best, o);
    }
    if (l < 16) {
        int kk = (int)(best & 1023ull);
        bestk_ws[r0 + l] = kk;
        out_idx[r0 + l]  = (float)kk;
    }
}

// ---------------- K3: gather + NCHW transpose ----------------
__global__ __launch_bounds__(256) void k3_gather(const float* __restrict__ embed,
                                                 const int* __restrict__ bestk,
                                                 float* __restrict__ out0) {
    __shared__ float tile[64][129];
    const int b   = blockIdx.x >> 4;
    const int hw0 = (blockIdx.x & 15) << 6;
    const int t   = threadIdx.x;
    const int n0  = b * HW_ + hw0;
#pragma unroll
    for (int i = 0; i < 32; ++i) {
        int idx = i * 256 + t;
        int hwl = idx >> 7, d = idx & 127;
        int k = bestk[n0 + hwl];
        tile[hwl][d] = embed[(size_t)k * 128 + d];
    }
    __syncthreads();
#pragma unroll
    for (int i = 0; i < 32; ++i) {
        int idx = i * 256 + t;
        int d = idx >> 6, hwl = idx & 63;
        out0[(((size_t)b * D_ + d) << 10) + hw0 + hwl] = tile[hwl][d];
    }
}

extern "C" void kernel_launch(void* const* d_in, const int* in_sizes, int n_in,
                              void* d_out, int out_size, void* d_ws, size_t ws_size,
                              hipStream_t stream) {
    const float* z     = (const float*)d_in[0];
    const float* pw    = (const float*)d_in[1];
    const float* pb    = (const float*)d_in[2];
    const float* embed = (const float*)d_in[3];

    float* out0 = (float*)d_out;
    float* out1 = (float*)d_out + (size_t)B_ * D_ * HW_;

    char* ws = (char*)d_ws;
    float*          zp    = (float*)ws;                                   // 32 MB
    unsigned short* zbf   = (unsigned short*)(ws + (32u << 20));          // 16 MB
    unsigned short* ebf   = (unsigned short*)(ws + (48u << 20));          // 256 KB
    float*          enorm = (float*)(ws + (48u << 20) + (256u << 10));    // 4 KB
    float*          znorm = (float*)(ws + (49u << 20));                   // 256 KB
    int*            bestk = (int*)  (ws + (50u << 20));                   // 256 KB

    hipLaunchKernelGGL(k0_norms,  dim3(4),    dim3(256), 0, stream, embed, enorm, ebf);
    hipLaunchKernelGGL(k1_proj,   dim3(1024), dim3(256), 0, stream, z, pw, pb, zp, zbf);
    hipLaunchKernelGGL(k0z_znorm, dim3(1024), dim3(256), 0, stream, zp, znorm);
    hipLaunchKernelGGL(k2_argmin, dim3(1024), dim3(256), 0, stream,
                       zbf, ebf, zp, embed, enorm, znorm, bestk, out1);
    hipLaunchKernelGGL(k3_gather, dim3(1024), dim3(256), 0, stream, embed, bestk, out0);
}